// Round 1
// baseline (165.346 us; speedup 1.0000x reference)
//
#include <hip/hip_runtime.h>
#include <hip/hip_bf16.h>

// BPTT diagonal RNN: u = X @ B^T  (bf16 MFMA GEMM), then chunked diagonal scan.
// T=8192, H=2048. Output h [T,H] f32 in d_out. d_ws: 1 MB chunk-carry buffer.

#define TDIM 8192
#define HDIM 2048
#define BM 128
#define BN 128
#define BK 32
#define LDK 40                 // padded LDS row length (bf16 elems): 80B rows, uniform banks
#define NT (HDIM / BK)         // 64 K-tiles
#define LCH 64                 // scan chunk length
#define GCH (TDIM / LCH)       // 128 chunks

typedef float f32x4 __attribute__((ext_vector_type(4)));
typedef short s16x8 __attribute__((ext_vector_type(8)));

static __device__ __forceinline__ short f2bf(float f) {
  __bf16 b = (__bf16)f;                 // RNE f32->bf16 (v_cvt on gfx950)
  return __builtin_bit_cast(short, b);
}

// ---------------- GEMM: U[t][j] = sum_k X[t][k] * Bm[j][k] ----------------
__global__ __launch_bounds__(256, 2) void gemm_bt(
    const float* __restrict__ X, const float* __restrict__ Bm,
    float* __restrict__ U) {
  __shared__ __align__(16) short As[2][BM * LDK];
  __shared__ __align__(16) short Bs[2][BN * LDK];

  // XCD-aware swizzle (nwg=1024, %8==0 -> bijective)
  const int wg  = blockIdx.x;
  const int cpx = (TDIM / BM) * (HDIM / BN) / 8;
  const int swz = (wg & 7) * cpx + (wg >> 3);
  const int tm = swz >> 4;              // / (HDIM/BN)
  const int tn = swz & 15;
  const int row0 = tm * BM, col0 = tn * BN;

  const int tid  = threadIdx.x;
  const int lane = tid & 63;
  const int wid  = tid >> 6;
  const int wr = (wid >> 1) * 64;       // 2x2 waves, each owns 64x64
  const int wc = (wid & 1) * 64;

  // staging: thread covers rows {srow, srow+64}, k-slice [sk, sk+8)
  const int srow = tid >> 2;            // 0..63
  const int sk   = (tid & 3) << 3;      // 0,8,16,24

  const float* gA  = X  + (row0 + srow) * HDIM + sk;
  const float* gA2 = gA + 64 * HDIM;
  const float* gB  = Bm + (col0 + srow) * HDIM + sk;
  const float* gB2 = gB + 64 * HDIM;

  f32x4 a00, a01, a10, a11, b00, b01, b10, b11;

#define LOADREG(kt) do {                                                      \
    const float* p;                                                           \
    p = gA  + (kt) * BK; a00 = *(const f32x4*)p; a01 = *(const f32x4*)(p + 4);\
    p = gA2 + (kt) * BK; a10 = *(const f32x4*)p; a11 = *(const f32x4*)(p + 4);\
    p = gB  + (kt) * BK; b00 = *(const f32x4*)p; b01 = *(const f32x4*)(p + 4);\
    p = gB2 + (kt) * BK; b10 = *(const f32x4*)p; b11 = *(const f32x4*)(p + 4);\
  } while (0)

#define CVT8(v, lo, hi) do {                                                  \
    v[0] = f2bf(lo[0]); v[1] = f2bf(lo[1]); v[2] = f2bf(lo[2]);               \
    v[3] = f2bf(lo[3]); v[4] = f2bf(hi[0]); v[5] = f2bf(hi[1]);               \
    v[6] = f2bf(hi[2]); v[7] = f2bf(hi[3]);                                   \
  } while (0)

#define DSWRITE(buf) do {                                                     \
    s16x8 v;                                                                  \
    CVT8(v, a00, a01); *(s16x8*)&As[buf][srow * LDK + sk] = v;                \
    CVT8(v, a10, a11); *(s16x8*)&As[buf][(srow + 64) * LDK + sk] = v;         \
    CVT8(v, b00, b01); *(s16x8*)&Bs[buf][srow * LDK + sk] = v;                \
    CVT8(v, b10, b11); *(s16x8*)&Bs[buf][(srow + 64) * LDK + sk] = v;         \
  } while (0)

  f32x4 acc[4][4] = {};

#define COMPUTE(buf) do {                                                     \
    const int r16 = lane & 15;                                                \
    const int ks  = (lane >> 4) * 8;                                          \
    s16x8 af[4], bfr[4];                                                      \
    _Pragma("unroll") for (int m = 0; m < 4; ++m)                             \
      af[m] = *(const s16x8*)&As[buf][(wr + m * 16 + r16) * LDK + ks];        \
    _Pragma("unroll") for (int n = 0; n < 4; ++n)                             \
      bfr[n] = *(const s16x8*)&Bs[buf][(wc + n * 16 + r16) * LDK + ks];       \
    _Pragma("unroll") for (int m = 0; m < 4; ++m)                             \
      _Pragma("unroll") for (int n = 0; n < 4; ++n)                           \
        acc[m][n] = __builtin_amdgcn_mfma_f32_16x16x32_bf16(                  \
            af[m], bfr[n], acc[m][n], 0, 0, 0);                               \
  } while (0)

  LOADREG(0);
  DSWRITE(0);
  __syncthreads();

#pragma unroll 2
  for (int kt = 0; kt < NT; ++kt) {
    const int cur = kt & 1;
    if (kt + 1 < NT) LOADREG(kt + 1);   // issue next-tile global loads early
    COMPUTE(cur);
    if (kt + 1 < NT) DSWRITE(cur ^ 1);  // prev reads of cur^1 fenced by last barrier
    __syncthreads();
  }

  // epilogue: C/D mapping col=lane&15, row=(lane>>4)*4+j  [m89-verified]
  const int crow = wr + ((lane >> 4) << 2);
  const int ccol = wc + (lane & 15);
#pragma unroll
  for (int m = 0; m < 4; ++m)
#pragma unroll
    for (int n = 0; n < 4; ++n)
#pragma unroll
      for (int j = 0; j < 4; ++j)
        U[(row0 + crow + m * 16 + j) * HDIM + (col0 + ccol + n * 16)] =
            acc[m][n][j];

#undef LOADREG
#undef CVT8
#undef DSWRITE
#undef COMPUTE
}

// ---------------- scan pass 1: per-chunk local scan end values ----------------
__global__ void scan_pass1(const float* __restrict__ U,
                           const float* __restrict__ lam,
                           float* __restrict__ e) {
  const int c = (blockIdx.y * 256 + threadIdx.x) * 4;
  const int j = blockIdx.x;
  const f32x4 l4 = *(const f32x4*)&lam[c];
  f32x4 h = {0.f, 0.f, 0.f, 0.f};
  const float* up = U + j * LCH * HDIM + c;
#pragma unroll 4
  for (int t = 0; t < LCH; ++t) {
    f32x4 u4 = *(const f32x4*)up;
    h = l4 * h + u4;
    up += HDIM;
  }
  *(f32x4*)&e[j * HDIM + c] = h;
}

// ---------------- scan pass 2: carry scan over chunks (in-place on e) --------
__global__ void scan_carry(float* __restrict__ e, const float* __restrict__ lam) {
  const int c = (blockIdx.x * 256 + threadIdx.x) * 4;
  const f32x4 l4 = *(const f32x4*)&lam[c];
  f32x4 p = l4;
#pragma unroll
  for (int i = 0; i < 6; ++i) p = p * p;   // lam^64 (6 squarings)
  f32x4 E = {0.f, 0.f, 0.f, 0.f};
  for (int j = 0; j < GCH; ++j) {
    f32x4 ej = *(const f32x4*)&e[j * HDIM + c];
    *(f32x4*)&e[j * HDIM + c] = E;         // carry into chunk j = E_{j-1}
    E = p * E + ej;
  }
}

// ---------------- scan pass 3: final scan with carry, in-place U -> h --------
__global__ void scan_pass3(float* __restrict__ U, const float* __restrict__ lam,
                           const float* __restrict__ carry) {
  const int c = (blockIdx.y * 256 + threadIdx.x) * 4;
  const int j = blockIdx.x;
  const f32x4 l4 = *(const f32x4*)&lam[c];
  f32x4 h = *(const f32x4*)&carry[j * HDIM + c];
  float* up = U + j * LCH * HDIM + c;
#pragma unroll 4
  for (int t = 0; t < LCH; ++t) {
    f32x4 u4 = *(const f32x4*)up;
    h = l4 * h + u4;
    *(f32x4*)up = h;
    up += HDIM;
  }
}

extern "C" void kernel_launch(void* const* d_in, const int* in_sizes, int n_in,
                              void* d_out, int out_size, void* d_ws, size_t ws_size,
                              hipStream_t stream) {
  const float* X   = (const float*)d_in[0];
  const float* lam = (const float*)d_in[1];
  const float* Bm  = (const float*)d_in[2];
  float* U = (float*)d_out;        // u then h, in-place
  float* e = (float*)d_ws;         // GCH*HDIM*4 = 1 MB

  gemm_bt<<<dim3((TDIM / BM) * (HDIM / BN)), dim3(256), 0, stream>>>(X, Bm, U);
  scan_pass1<<<dim3(GCH, HDIM / 1024), dim3(256), 0, stream>>>(U, lam, e);
  scan_carry<<<dim3(HDIM / 1024), dim3(256), 0, stream>>>(e, lam);
  scan_pass3<<<dim3(GCH, HDIM / 1024), dim3(256), 0, stream>>>(U, lam, e);
}

// Round 2
// 146.079 us; speedup vs baseline: 1.1319x; 1.1319x over previous
//
#include <hip/hip_runtime.h>
#include <hip/hip_bf16.h>

// BPTT diagonal RNN: u = X @ B^T, then chunked diagonal scan (h_t = lam*h_{t-1}+u_t).
// R2: pre-convert X,B to bf16 in d_ws, then m97-structure GEMM
// (global_load_lds width=16, 128^2 tile, 2-phase loop, 1 barrier/K-step).

#define TDIM 8192
#define HDIM 2048
#define BM 128
#define BN 128
#define BK 32
#define NT (HDIM / BK)         // 64 K-tiles
#define LCH 64                 // scan chunk length
#define GCH (TDIM / LCH)       // 128 chunks

#define XBF_BYTES (TDIM * HDIM * 2)            // 33554432
#define BBF_BYTES (HDIM * HDIM * 2)            // 8388608
#define E_BYTES   (GCH * HDIM * 4)             // 1048576
#define WS_NEED   ((size_t)XBF_BYTES + BBF_BYTES + E_BYTES)

typedef float f32x4 __attribute__((ext_vector_type(4)));
typedef short s16x8 __attribute__((ext_vector_type(8)));

static __device__ __forceinline__ short f2bf(float f) {
  __bf16 b = (__bf16)f;                 // RNE f32->bf16
  return __builtin_bit_cast(short, b);
}

// ---------------- f32 -> bf16 convert (memory-bound, vectorized) ----------------
__global__ void cvt_f32_bf16(const float* __restrict__ src, short* __restrict__ dst,
                             int n8) {
  int i = blockIdx.x * blockDim.x + threadIdx.x;
  const int stride = gridDim.x * blockDim.x;
  for (; i < n8; i += stride) {
    f32x4 a = *(const f32x4*)(src + (size_t)i * 8);
    f32x4 b = *(const f32x4*)(src + (size_t)i * 8 + 4);
    s16x8 v;
    v[0] = f2bf(a[0]); v[1] = f2bf(a[1]); v[2] = f2bf(a[2]); v[3] = f2bf(a[3]);
    v[4] = f2bf(b[0]); v[5] = f2bf(b[1]); v[6] = f2bf(b[2]); v[7] = f2bf(b[3]);
    *(s16x8*)(dst + (size_t)i * 8) = v;
  }
}

// ---------------- bf16 GEMM, m97 structure: U[t][j] = sum_k Xb[t][k]*Bb[j][k] ----
__global__ __launch_bounds__(256, 3) void gemm_bf16(
    const short* __restrict__ Xb, const short* __restrict__ Bb,
    float* __restrict__ U) {
  __shared__ __align__(16) short As[2][BM * BK];   // linear [row][k], 64B rows
  __shared__ __align__(16) short Bs[2][BN * BK];

  // XCD-aware swizzle (nwg=1024, %8==0 -> bijective)
  const int wg  = blockIdx.x;
  const int cpx = (TDIM / BM) * (HDIM / BN) / 8;   // 128
  const int swz = (wg & 7) * cpx + (wg >> 3);
  const int tm = swz >> 4;
  const int tn = swz & 15;
  const int row0 = tm * BM, col0 = tn * BN;

  const int tid  = threadIdx.x;
  const int lane = tid & 63;
  const int wid  = tid >> 6;
  const int wr = (wid >> 1) * 64;       // 2x2 waves, each owns 64x64
  const int wc = (wid & 1) * 64;

  // staging: thread t covers LDS bytes [t*16, t*16+16) of each 64-row half-tile
  const int srow = tid >> 2;            // 0..63
  const int sk8  = (tid & 3) * 8;       // short offset in row

  const short* gA = Xb + (size_t)(row0 + srow) * HDIM + sk8;
  const short* gB = Bb + (size_t)(col0 + srow) * HDIM + sk8;

#define GLDS(gp, lp)                                                          \
  __builtin_amdgcn_global_load_lds(                                          \
      (const __attribute__((address_space(1))) void*)(gp),                    \
      (__attribute__((address_space(3))) void*)(lp), 16, 0, 0)

#define STAGE(buf, kt) do {                                                   \
    const short* a0 = gA + (kt) * BK;                                         \
    const short* b0 = gB + (kt) * BK;                                         \
    GLDS(a0,             &As[buf][srow * BK + sk8]);                          \
    GLDS(a0 + 64 * HDIM, &As[buf][(srow + 64) * BK + sk8]);                   \
    GLDS(b0,             &Bs[buf][srow * BK + sk8]);                          \
    GLDS(b0 + 64 * HDIM, &Bs[buf][(srow + 64) * BK + sk8]);                   \
  } while (0)

  f32x4 acc[4][4] = {};
  const int r16 = lane & 15;
  const int ks  = (lane >> 4) * 8;      // short offset: 16B per lane-group

#define COMPUTE(buf) do {                                                     \
    s16x8 af[4], bfr[4];                                                      \
    _Pragma("unroll") for (int m = 0; m < 4; ++m)                             \
      af[m] = *(const s16x8*)&As[buf][(wr + m * 16 + r16) * BK + ks];         \
    _Pragma("unroll") for (int n = 0; n < 4; ++n)                             \
      bfr[n] = *(const s16x8*)&Bs[buf][(wc + n * 16 + r16) * BK + ks];        \
    _Pragma("unroll") for (int m = 0; m < 4; ++m)                             \
      _Pragma("unroll") for (int n = 0; n < 4; ++n)                           \
        acc[m][n] = __builtin_amdgcn_mfma_f32_16x16x32_bf16(                  \
            af[m], bfr[n], acc[m][n], 0, 0, 0);                               \
  } while (0)

  STAGE(0, 0);
  __syncthreads();                      // drains vmcnt(0): buf0 ready
  int cur = 0;
#pragma unroll 2
  for (int kt = 0; kt + 1 < NT; ++kt) {
    STAGE(cur ^ 1, kt + 1);             // async loads into other buffer
    COMPUTE(cur);                       // ds_read + 16 MFMA
    __syncthreads();                    // vmcnt(0)+lgkm+barrier: next buf ready
    cur ^= 1;
  }
  COMPUTE(cur);

  // epilogue: C/D mapping col=lane&15, row=(lane>>4)*4+j  [validated in R1]
  const int crow = wr + ((lane >> 4) << 2);
  const int ccol = wc + (lane & 15);
#pragma unroll
  for (int m = 0; m < 4; ++m)
#pragma unroll
    for (int n = 0; n < 4; ++n)
#pragma unroll
      for (int j = 0; j < 4; ++j)
        U[(size_t)(row0 + crow + m * 16 + j) * HDIM + (col0 + ccol + n * 16)] =
            acc[m][n][j];

#undef GLDS
#undef STAGE
#undef COMPUTE
}

// ---------------- fallback GEMM (R1, f32 reg-staging) -----------------------
__global__ __launch_bounds__(256, 2) void gemm_f32_fb(
    const float* __restrict__ X, const float* __restrict__ Bm,
    float* __restrict__ U) {
#define LDK 40
  __shared__ __align__(16) short As[2][BM * LDK];
  __shared__ __align__(16) short Bs[2][BN * LDK];
  const int wg  = blockIdx.x;
  const int cpx = (TDIM / BM) * (HDIM / BN) / 8;
  const int swz = (wg & 7) * cpx + (wg >> 3);
  const int tm = swz >> 4;
  const int tn = swz & 15;
  const int row0 = tm * BM, col0 = tn * BN;
  const int tid  = threadIdx.x;
  const int lane = tid & 63;
  const int wid  = tid >> 6;
  const int wr = (wid >> 1) * 64;
  const int wc = (wid & 1) * 64;
  const int srow = tid >> 2;
  const int sk   = (tid & 3) << 3;
  const float* gA  = X  + (size_t)(row0 + srow) * HDIM + sk;
  const float* gA2 = gA + 64 * HDIM;
  const float* gB  = Bm + (size_t)(col0 + srow) * HDIM + sk;
  const float* gB2 = gB + 64 * HDIM;
  f32x4 a00, a01, a10, a11, b00, b01, b10, b11;
#define LOADREG(kt) do {                                                      \
    const float* p;                                                           \
    p = gA  + (kt) * BK; a00 = *(const f32x4*)p; a01 = *(const f32x4*)(p + 4);\
    p = gA2 + (kt) * BK; a10 = *(const f32x4*)p; a11 = *(const f32x4*)(p + 4);\
    p = gB  + (kt) * BK; b00 = *(const f32x4*)p; b01 = *(const f32x4*)(p + 4);\
    p = gB2 + (kt) * BK; b10 = *(const f32x4*)p; b11 = *(const f32x4*)(p + 4);\
  } while (0)
#define CVT8(v, lo, hi) do {                                                  \
    v[0] = f2bf(lo[0]); v[1] = f2bf(lo[1]); v[2] = f2bf(lo[2]);               \
    v[3] = f2bf(lo[3]); v[4] = f2bf(hi[0]); v[5] = f2bf(hi[1]);               \
    v[6] = f2bf(hi[2]); v[7] = f2bf(hi[3]);                                   \
  } while (0)
#define DSWRITE(buf) do {                                                     \
    s16x8 v;                                                                  \
    CVT8(v, a00, a01); *(s16x8*)&As[buf][srow * LDK + sk] = v;                \
    CVT8(v, a10, a11); *(s16x8*)&As[buf][(srow + 64) * LDK + sk] = v;         \
    CVT8(v, b00, b01); *(s16x8*)&Bs[buf][srow * LDK + sk] = v;                \
    CVT8(v, b10, b11); *(s16x8*)&Bs[buf][(srow + 64) * LDK + sk] = v;         \
  } while (0)
  f32x4 acc[4][4] = {};
#define COMPUTE(buf) do {                                                     \
    const int r16 = lane & 15;                                                \
    const int ks  = (lane >> 4) * 8;                                          \
    s16x8 af[4], bfr[4];                                                      \
    _Pragma("unroll") for (int m = 0; m < 4; ++m)                             \
      af[m] = *(const s16x8*)&As[buf][(wr + m * 16 + r16) * LDK + ks];        \
    _Pragma("unroll") for (int n = 0; n < 4; ++n)                             \
      bfr[n] = *(const s16x8*)&Bs[buf][(wc + n * 16 + r16) * LDK + ks];       \
    _Pragma("unroll") for (int m = 0; m < 4; ++m)                             \
      _Pragma("unroll") for (int n = 0; n < 4; ++n)                           \
        acc[m][n] = __builtin_amdgcn_mfma_f32_16x16x32_bf16(                  \
            af[m], bfr[n], acc[m][n], 0, 0, 0);                               \
  } while (0)
  LOADREG(0);
  DSWRITE(0);
  __syncthreads();
#pragma unroll 2
  for (int kt = 0; kt < NT; ++kt) {
    const int cur = kt & 1;
    if (kt + 1 < NT) LOADREG(kt + 1);
    COMPUTE(cur);
    if (kt + 1 < NT) DSWRITE(cur ^ 1);
    __syncthreads();
  }
  const int crow = wr + ((lane >> 4) << 2);
  const int ccol = wc + (lane & 15);
#pragma unroll
  for (int m = 0; m < 4; ++m)
#pragma unroll
    for (int n = 0; n < 4; ++n)
#pragma unroll
      for (int j = 0; j < 4; ++j)
        U[(size_t)(row0 + crow + m * 16 + j) * HDIM + (col0 + ccol + n * 16)] =
            acc[m][n][j];
#undef LOADREG
#undef CVT8
#undef DSWRITE
#undef COMPUTE
#undef LDK
}

// ---------------- scan pass 1: per-chunk local scan end values ----------------
__global__ void scan_pass1(const float* __restrict__ U,
                           const float* __restrict__ lam,
                           float* __restrict__ e) {
  const int c = (blockIdx.y * 256 + threadIdx.x) * 4;
  const int j = blockIdx.x;
  const f32x4 l4 = *(const f32x4*)&lam[c];
  f32x4 h = {0.f, 0.f, 0.f, 0.f};
  const float* up = U + (size_t)j * LCH * HDIM + c;
#pragma unroll 4
  for (int t = 0; t < LCH; ++t) {
    f32x4 u4 = *(const f32x4*)up;
    h = l4 * h + u4;
    up += HDIM;
  }
  *(f32x4*)&e[(size_t)j * HDIM + c] = h;
}

// ---------------- scan pass 2: carry scan over chunks (in-place on e) --------
__global__ void scan_carry(float* __restrict__ e, const float* __restrict__ lam) {
  const int c = (blockIdx.x * 256 + threadIdx.x) * 4;
  const f32x4 l4 = *(const f32x4*)&lam[c];
  f32x4 p = l4;
#pragma unroll
  for (int i = 0; i < 6; ++i) p = p * p;   // lam^64
  f32x4 E = {0.f, 0.f, 0.f, 0.f};
  for (int j = 0; j < GCH; ++j) {
    f32x4 ej = *(const f32x4*)&e[(size_t)j * HDIM + c];
    *(f32x4*)&e[(size_t)j * HDIM + c] = E;  // carry into chunk j = E_{j-1}
    E = p * E + ej;
  }
}

// ---------------- scan pass 3: final scan with carry, in-place U -> h --------
__global__ void scan_pass3(float* __restrict__ U, const float* __restrict__ lam,
                           const float* __restrict__ carry) {
  const int c = (blockIdx.y * 256 + threadIdx.x) * 4;
  const int j = blockIdx.x;
  const f32x4 l4 = *(const f32x4*)&lam[c];
  f32x4 h = *(const f32x4*)&carry[(size_t)j * HDIM + c];
  float* up = U + (size_t)j * LCH * HDIM + c;
#pragma unroll 4
  for (int t = 0; t < LCH; ++t) {
    f32x4 u4 = *(const f32x4*)up;
    h = l4 * h + u4;
    *(f32x4*)up = h;
    up += HDIM;
  }
}

extern "C" void kernel_launch(void* const* d_in, const int* in_sizes, int n_in,
                              void* d_out, int out_size, void* d_ws, size_t ws_size,
                              hipStream_t stream) {
  const float* X   = (const float*)d_in[0];
  const float* lam = (const float*)d_in[1];
  const float* Bm  = (const float*)d_in[2];
  float* U = (float*)d_out;              // u then h, in-place

  if (ws_size >= WS_NEED) {
    short* Xb = (short*)d_ws;
    short* Bb = (short*)((char*)d_ws + XBF_BYTES);
    float* e  = (float*)((char*)d_ws + XBF_BYTES + BBF_BYTES);

    cvt_f32_bf16<<<dim3(2048), dim3(256), 0, stream>>>(X, Xb, TDIM * HDIM / 8);
    cvt_f32_bf16<<<dim3(2048), dim3(256), 0, stream>>>(Bm, Bb, HDIM * HDIM / 8);
    gemm_bf16<<<dim3((TDIM / BM) * (HDIM / BN)), dim3(256), 0, stream>>>(Xb, Bb, U);
    scan_pass1<<<dim3(GCH, HDIM / 1024), dim3(256), 0, stream>>>(U, lam, e);
    scan_carry<<<dim3(HDIM / 1024), dim3(256), 0, stream>>>(e, lam);
    scan_pass3<<<dim3(GCH, HDIM / 1024), dim3(256), 0, stream>>>(U, lam, e);
  } else {
    float* e = (float*)d_ws;             // 1 MB
    gemm_f32_fb<<<dim3((TDIM / BM) * (HDIM / BN)), dim3(256), 0, stream>>>(X, Bm, U);
    scan_pass1<<<dim3(GCH, HDIM / 1024), dim3(256), 0, stream>>>(U, lam, e);
    scan_carry<<<dim3(HDIM / 1024), dim3(256), 0, stream>>>(e, lam);
    scan_pass3<<<dim3(GCH, HDIM / 1024), dim3(256), 0, stream>>>(U, lam, e);
  }
}

// Round 3
// 132.119 us; speedup vs baseline: 1.2515x; 1.1057x over previous
//
#include <hip/hip_runtime.h>
#include <hip/hip_bf16.h>

// BPTT diagonal RNN: u = X @ B^T (bf16 MFMA), then chunked diagonal scan.
// R3: 256^2 deep-pipelined GEMM (4-slot LDS ring, counted vmcnt, raw barriers,
// setprio, T2 swizzle, XCD swizzle) + fused single cvt kernel.

#define TDIM 8192
#define HDIM 2048
#define BM 256
#define BN 256
#define BK 32
#define NT (HDIM / BK)         // 64 K-tiles
#define ASLOT 8192             // shorts per A slot (256*32)
#define BSLOT 8192
#define LCH 64                 // scan chunk length
#define GCH (TDIM / LCH)       // 128 chunks

#define XBF_BYTES (TDIM * HDIM * 2)
#define BBF_BYTES (HDIM * HDIM * 2)
#define E_BYTES   (GCH * HDIM * 4)
#define WS_NEED   ((size_t)XBF_BYTES + BBF_BYTES + E_BYTES)

typedef float f32x4 __attribute__((ext_vector_type(4)));
typedef short s16x8 __attribute__((ext_vector_type(8)));

static __device__ __forceinline__ short f2bf(float f) {
  __bf16 b = (__bf16)f;
  return __builtin_bit_cast(short, b);
}

#define SB()   asm volatile("s_barrier" ::: "memory")
#define VMW(n) asm volatile("s_waitcnt vmcnt(" #n ")" ::: "memory")
#define GL(gp, lp)                                                            \
  __builtin_amdgcn_global_load_lds(                                           \
      (const __attribute__((address_space(1))) void*)(gp),                    \
      (__attribute__((address_space(3))) void*)(lp), 16, 0, 0)

// ---------------- fused f32 -> bf16 convert for X and B ----------------
__global__ void cvt_all(const float* __restrict__ X, const float* __restrict__ Bm,
                        short* __restrict__ Xb, short* __restrict__ Bbf) {
  const int XN8 = TDIM * HDIM / 8;
  const int BN8 = HDIM * HDIM / 8;
  const int stride = gridDim.x * blockDim.x;
  for (int i = blockIdx.x * blockDim.x + threadIdx.x; i < XN8 + BN8; i += stride) {
    const float* s;
    short* d;
    int k;
    if (i < XN8) { s = X; d = Xb; k = i; }
    else         { s = Bm; d = Bbf; k = i - XN8; }
    f32x4 a = *(const f32x4*)(s + (size_t)k * 8);
    f32x4 b = *(const f32x4*)(s + (size_t)k * 8 + 4);
    s16x8 v;
    v[0] = f2bf(a[0]); v[1] = f2bf(a[1]); v[2] = f2bf(a[2]); v[3] = f2bf(a[3]);
    v[4] = f2bf(b[0]); v[5] = f2bf(b[1]); v[6] = f2bf(b[2]); v[7] = f2bf(b[3]);
    *(s16x8*)(d + (size_t)k * 8) = v;
  }
}

// ---------------- deep-pipelined 256^2 GEMM: U = Xb @ Bb^T ----------------
// 8 waves (2Mx4N), per-wave 128x64 out. BK=32, 4-slot LDS ring (128 KiB).
// Iter j: compute K-tile j (slot j&3), stage K-tile j+3 (slot (j-1)&3, freed
// in iter j-1). vmcnt(8) at iter end gates K-tile j+1 (its 4 loads are >=8 old).
__global__ __launch_bounds__(512, 2) void gemm8p(
    const short* __restrict__ Xb, const short* __restrict__ Bb,
    float* __restrict__ U) {
  extern __shared__ __align__(16) short smem[];
  short* As = smem;             // 4 slots x 8192 shorts (64 KiB)
  short* Bs = smem + 4 * ASLOT; // 4 slots x 8192 shorts (64 KiB)

  // XCD-aware swizzle: nwg=256, each XCD gets a 4(tm) x 8(tn) rectangle
  const int wg  = blockIdx.x;
  const int swz = (wg & 7) * 32 + (wg >> 3);
  const int tm = swz >> 3;              // 0..31
  const int tn = swz & 7;               // 0..7
  const int row0 = tm * BM, col0 = tn * BN;

  const int tid  = threadIdx.x;
  const int lane = tid & 63;
  const int wid  = tid >> 6;
  const int wr = (wid >> 2) * 128;      // 2 m-groups
  const int wc = (wid & 3) * 64;        // 4 n-groups
  const int r16 = lane & 15;
  const int ks8 = (lane >> 4) * 8;      // 16B k-slice (shorts)

  // fragment read offsets (within slot), T2-XOR-swizzled
  int offA[8], offB[4];
#pragma unroll
  for (int m = 0; m < 8; ++m) {
    const int r = wr + m * 16 + r16;
    offA[m] = r * BK + (ks8 ^ ((r & 3) * 8));
  }
#pragma unroll
  for (int n = 0; n < 4; ++n) {
    const int r = wc + n * 16 + r16;
    offB[n] = r * BK + (ks8 ^ ((r & 3) * 8));
  }

  // staging: unit = 128 rows x 32 k (8 KiB) = 1 gload_lds/thread.
  // LDS dest linear tid*16B; global source pre-swizzled (inverse of read XOR).
  const int srow = tid >> 2;            // 0..127
  const int sg   = (tid & 3) ^ (srow & 3);
  const short* gA0 = Xb + (size_t)(row0 + srow) * HDIM + sg * 8;
  const short* gA1 = gA0 + (size_t)128 * HDIM;
  const short* gB0 = Bb + (size_t)(col0 + srow) * HDIM + sg * 8;
  const short* gB1 = gB0 + (size_t)128 * HDIM;

  f32x4 acc[8][4] = {};

  // prologue: stage K-tiles 0,1,2 -> slots 0,1,2 (12 loads), wait K0, barrier
#pragma unroll
  for (int k = 0; k < 3; ++k) {
    GL(gA0 + k * BK, &As[k * ASLOT + tid * 8]);
    GL(gA1 + k * BK, &As[k * ASLOT + 4096 + tid * 8]);
    GL(gB0 + k * BK, &Bs[k * BSLOT + tid * 8]);
    GL(gB1 + k * BK, &Bs[k * BSLOT + 4096 + tid * 8]);
  }
  VMW(8);
  SB();

#define ITER(J_, ST_, VMA_, SBF_) do {                                        \
    const int sc_ = (J_) & 3;                                                 \
    const int si_ = ((J_) + 3) & 3;                                           \
    const int ko_ = ((J_) + 3) * BK;                                          \
    s16x8 af[4], bfv[4];                                                      \
    _Pragma("unroll") for (int m = 0; m < 4; ++m)                             \
      af[m] = *(const s16x8*)&As[sc_ * ASLOT + offA[m]];                      \
    _Pragma("unroll") for (int n = 0; n < 4; ++n)                             \
      bfv[n] = *(const s16x8*)&Bs[sc_ * BSLOT + offB[n]];                     \
    if (ST_) {                                                                \
      GL(gA0 + ko_, &As[si_ * ASLOT + tid * 8]);                              \
      GL(gA1 + ko_, &As[si_ * ASLOT + 4096 + tid * 8]);                       \
    }                                                                         \
    SB();                                                                     \
    __builtin_amdgcn_s_setprio(1);                                            \
    _Pragma("unroll") for (int m = 0; m < 4; ++m)                             \
      _Pragma("unroll") for (int n = 0; n < 4; ++n)                           \
        acc[m][n] = __builtin_amdgcn_mfma_f32_16x16x32_bf16(                  \
            af[m], bfv[n], acc[m][n], 0, 0, 0);                               \
    __builtin_amdgcn_s_setprio(0);                                            \
    SB();                                                                     \
    _Pragma("unroll") for (int m = 0; m < 4; ++m)                             \
      af[m] = *(const s16x8*)&As[sc_ * ASLOT + offA[4 + m]];                  \
    if (ST_) {                                                                \
      GL(gB0 + ko_, &Bs[si_ * BSLOT + tid * 8]);                              \
      GL(gB1 + ko_, &Bs[si_ * BSLOT + 4096 + tid * 8]);                       \
    }                                                                         \
    SB();                                                                     \
    __builtin_amdgcn_s_setprio(1);                                            \
    _Pragma("unroll") for (int m = 0; m < 4; ++m)                             \
      _Pragma("unroll") for (int n = 0; n < 4; ++n)                           \
        acc[4 + m][n] = __builtin_amdgcn_mfma_f32_16x16x32_bf16(              \
            af[m], bfv[n], acc[4 + m][n], 0, 0, 0);                           \
    __builtin_amdgcn_s_setprio(0);                                            \
    VMA_;                                                                     \
    SBF_;                                                                     \
  } while (0)

#pragma unroll 4
  for (int j = 0; j < NT - 4; ++j) ITER(j, true, VMW(8), SB());
  ITER(NT - 4, true,  VMW(8), SB());   // stages K-tile NT-1
  ITER(NT - 3, false, VMW(4), SB());
  ITER(NT - 2, false, VMW(0), SB());
  ITER(NT - 1, false, (void)0, (void)0);
#undef ITER

  // epilogue: C/D mapping col=lane&15, row=(lane>>4)*4+j [verified R1/R2]
  const int crow = row0 + wr + ((lane >> 4) << 2);
  const int ccol = col0 + wc + r16;
#pragma unroll
  for (int m = 0; m < 8; ++m)
#pragma unroll
    for (int n = 0; n < 4; ++n)
#pragma unroll
      for (int j = 0; j < 4; ++j)
        U[(size_t)(crow + m * 16 + j) * HDIM + ccol + n * 16] = acc[m][n][j];
}

// ---------------- fallback GEMM (R1, f32 reg-staging, proven) ---------------
__global__ __launch_bounds__(256, 2) void gemm_f32_fb(
    const float* __restrict__ X, const float* __restrict__ Bm,
    float* __restrict__ U) {
#define LDK 40
#define FBM 128
#define FBN 128
  __shared__ __align__(16) short As[2][FBM * LDK];
  __shared__ __align__(16) short Bs[2][FBN * LDK];
  const int wg  = blockIdx.x;
  const int cpx = (TDIM / FBM) * (HDIM / FBN) / 8;
  const int swz = (wg & 7) * cpx + (wg >> 3);
  const int tm = swz >> 4;
  const int tn = swz & 15;
  const int row0 = tm * FBM, col0 = tn * FBN;
  const int tid  = threadIdx.x;
  const int lane = tid & 63;
  const int wid  = tid >> 6;
  const int wr = (wid >> 1) * 64;
  const int wc = (wid & 1) * 64;
  const int srow = tid >> 2;
  const int sk   = (tid & 3) << 3;
  const float* gA  = X  + (size_t)(row0 + srow) * HDIM + sk;
  const float* gA2 = gA + 64 * HDIM;
  const float* gB  = Bm + (size_t)(col0 + srow) * HDIM + sk;
  const float* gB2 = gB + 64 * HDIM;
  f32x4 a00, a01, a10, a11, b00, b01, b10, b11;
#define LOADREG(kt) do {                                                      \
    const float* p;                                                           \
    p = gA  + (kt) * BK; a00 = *(const f32x4*)p; a01 = *(const f32x4*)(p + 4);\
    p = gA2 + (kt) * BK; a10 = *(const f32x4*)p; a11 = *(const f32x4*)(p + 4);\
    p = gB  + (kt) * BK; b00 = *(const f32x4*)p; b01 = *(const f32x4*)(p + 4);\
    p = gB2 + (kt) * BK; b10 = *(const f32x4*)p; b11 = *(const f32x4*)(p + 4);\
  } while (0)
#define CVT8(v, lo, hi) do {                                                  \
    v[0] = f2bf(lo[0]); v[1] = f2bf(lo[1]); v[2] = f2bf(lo[2]);               \
    v[3] = f2bf(lo[3]); v[4] = f2bf(hi[0]); v[5] = f2bf(hi[1]);               \
    v[6] = f2bf(hi[2]); v[7] = f2bf(hi[3]);                                   \
  } while (0)
#define DSWRITE(buf) do {                                                     \
    s16x8 v;                                                                  \
    CVT8(v, a00, a01); *(s16x8*)&As[buf][srow * LDK + sk] = v;                \
    CVT8(v, a10, a11); *(s16x8*)&As[buf][(srow + 64) * LDK + sk] = v;         \
    CVT8(v, b00, b01); *(s16x8*)&Bs[buf][srow * LDK + sk] = v;                \
    CVT8(v, b10, b11); *(s16x8*)&Bs[buf][(srow + 64) * LDK + sk] = v;         \
  } while (0)
  f32x4 acc[4][4] = {};
#define COMPUTE(buf) do {                                                     \
    const int r16_ = lane & 15;                                               \
    const int ks_  = (lane >> 4) * 8;                                         \
    s16x8 af[4], bfr[4];                                                      \
    _Pragma("unroll") for (int m = 0; m < 4; ++m)                             \
      af[m] = *(const s16x8*)&As[buf][(wr + m * 16 + r16_) * LDK + ks_];      \
    _Pragma("unroll") for (int n = 0; n < 4; ++n)                             \
      bfr[n] = *(const s16x8*)&Bs[buf][(wc + n * 16 + r16_) * LDK + ks_];     \
    _Pragma("unroll") for (int m = 0; m < 4; ++m)                             \
      _Pragma("unroll") for (int n = 0; n < 4; ++n)                           \
        acc[m][n] = __builtin_amdgcn_mfma_f32_16x16x32_bf16(                  \
            af[m], bfr[n], acc[m][n], 0, 0, 0);                               \
  } while (0)
  LOADREG(0);
  DSWRITE(0);
  __syncthreads();
#pragma unroll 2
  for (int kt = 0; kt < NT; ++kt) {
    const int cur = kt & 1;
    if (kt + 1 < NT) LOADREG(kt + 1);
    COMPUTE(cur);
    if (kt + 1 < NT) DSWRITE(cur ^ 1);
    __syncthreads();
  }
  const int crow = wr + ((lane >> 4) << 2);
  const int ccol = wc + (lane & 15);
#pragma unroll
  for (int m = 0; m < 4; ++m)
#pragma unroll
    for (int n = 0; n < 4; ++n)
#pragma unroll
      for (int j = 0; j < 4; ++j)
        U[(size_t)(row0 + crow + m * 16 + j) * HDIM + (col0 + ccol + n * 16)] =
            acc[m][n][j];
#undef LOADREG
#undef CVT8
#undef DSWRITE
#undef COMPUTE
#undef LDK
#undef FBM
#undef FBN
}

// ---------------- scan pass 1: per-chunk local scan end values ---------------
__global__ void scan_pass1(const float* __restrict__ U,
                           const float* __restrict__ lam,
                           float* __restrict__ e) {
  const int c = (blockIdx.y * 256 + threadIdx.x) * 4;
  const int j = blockIdx.x;
  const f32x4 l4 = *(const f32x4*)&lam[c];
  f32x4 h = {0.f, 0.f, 0.f, 0.f};
  const float* up = U + (size_t)j * LCH * HDIM + c;
#pragma unroll 4
  for (int t = 0; t < LCH; ++t) {
    f32x4 u4 = *(const f32x4*)up;
    h = l4 * h + u4;
    up += HDIM;
  }
  *(f32x4*)&e[(size_t)j * HDIM + c] = h;
}

// ---------------- scan pass 2: carry scan over chunks (in-place on e) --------
__global__ void scan_carry(float* __restrict__ e, const float* __restrict__ lam) {
  const int c = (blockIdx.x * 256 + threadIdx.x) * 4;
  const f32x4 l4 = *(const f32x4*)&lam[c];
  f32x4 p = l4;
#pragma unroll
  for (int i = 0; i < 6; ++i) p = p * p;   // lam^64
  f32x4 E = {0.f, 0.f, 0.f, 0.f};
  for (int j = 0; j < GCH; ++j) {
    f32x4 ej = *(const f32x4*)&e[(size_t)j * HDIM + c];
    *(f32x4*)&e[(size_t)j * HDIM + c] = E;  // carry into chunk j = E_{j-1}
    E = p * E + ej;
  }
}

// ---------------- scan pass 3: final scan with carry, in-place U -> h --------
__global__ void scan_pass3(float* __restrict__ U, const float* __restrict__ lam,
                           const float* __restrict__ carry) {
  const int c = (blockIdx.y * 256 + threadIdx.x) * 4;
  const int j = blockIdx.x;
  const f32x4 l4 = *(const f32x4*)&lam[c];
  f32x4 h = *(const f32x4*)&carry[(size_t)j * HDIM + c];
  float* up = U + (size_t)j * LCH * HDIM + c;
#pragma unroll 4
  for (int t = 0; t < LCH; ++t) {
    f32x4 u4 = *(const f32x4*)up;
    h = l4 * h + u4;
    *(f32x4*)up = h;
    up += HDIM;
  }
}

extern "C" void kernel_launch(void* const* d_in, const int* in_sizes, int n_in,
                              void* d_out, int out_size, void* d_ws, size_t ws_size,
                              hipStream_t stream) {
  const float* X   = (const float*)d_in[0];
  const float* lam = (const float*)d_in[1];
  const float* Bm  = (const float*)d_in[2];
  float* U = (float*)d_out;

  if (ws_size >= WS_NEED) {
    short* Xb = (short*)d_ws;
    short* Bb = (short*)((char*)d_ws + XBF_BYTES);
    float* e  = (float*)((char*)d_ws + XBF_BYTES + BBF_BYTES);

    // allow 128 KiB dynamic LDS (idempotent, host-side, capture-safe)
    hipFuncSetAttribute((const void*)gemm8p,
                        hipFuncAttributeMaxDynamicSharedMemorySize, 131072);

    cvt_all<<<dim3(4096), dim3(256), 0, stream>>>(X, Bm, Xb, Bb);
    gemm8p<<<dim3((TDIM / BM) * (HDIM / BN)), dim3(512), 131072, stream>>>(Xb, Bb, U);
    scan_pass1<<<dim3(GCH, HDIM / 1024), dim3(256), 0, stream>>>(U, lam, e);
    scan_carry<<<dim3(HDIM / 1024), dim3(256), 0, stream>>>(e, lam);
    scan_pass3<<<dim3(GCH, HDIM / 1024), dim3(256), 0, stream>>>(U, lam, e);
  } else {
    float* e = (float*)d_ws;
    gemm_f32_fb<<<dim3((TDIM / 128) * (HDIM / 128)), dim3(256), 0, stream>>>(X, Bm, U);
    scan_pass1<<<dim3(GCH, HDIM / 1024), dim3(256), 0, stream>>>(U, lam, e);
    scan_carry<<<dim3(HDIM / 1024), dim3(256), 0, stream>>>(e, lam);
    scan_pass3<<<dim3(GCH, HDIM / 1024), dim3(256), 0, stream>>>(U, lam, e);
  }
}

// Round 4
// 119.143 us; speedup vs baseline: 1.3878x; 1.1089x over previous
//
#include <hip/hip_runtime.h>
#include <hip/hip_bf16.h>

// BPTT diagonal RNN: u = X @ B^T, h_t = lam*h_{t-1} + u_t (chunked scan).
// R4: single fused GEMM reads f32 X,B directly (reg-staged f32->bf16 cvt into
// LDS, T14 issue-early/consume-late), BK=64 conflict-free XOR swizzle,
// 2-slot dbuf, 1 barrier/iter. No separate cvt pass. Scans unchanged.

#define TDIM 8192
#define HDIM 2048
#define BM 256
#define BN 256
#define KT 64                  // K per iter (floats)
#define NIT (HDIM / KT)        // 32 iters
#define SLOT 16384             // shorts per LDS slot (256 rows x 64 k)
#define LCH 64                 // scan chunk length
#define GCH (TDIM / LCH)       // 128 chunks

typedef float f32x4 __attribute__((ext_vector_type(4)));
typedef short s16x4 __attribute__((ext_vector_type(4)));
typedef short s16x8 __attribute__((ext_vector_type(8)));

static __device__ __forceinline__ short f2bf(float f) {
  __bf16 b = (__bf16)f;                 // RNE f32->bf16
  return __builtin_bit_cast(short, b);
}

// ---------------- fused GEMM: U[t][j] = sum_k X[t][k] * Bm[j][k] ------------
// 8 waves (2Mx4N), per-wave out 128x64 (8m x 4n frags of 16x16).
// LDS rows = 64 shorts (128B) = 8 x 16B slots; physical slot = logical ^ (row&7)
// -> conflict-free ds_read_b128 frags AND conflict-free ds_write staging.
__global__ __launch_bounds__(512, 2) void gemm_fused(
    const float* __restrict__ X, const float* __restrict__ Bm,
    float* __restrict__ U) {
  extern __shared__ __align__(16) short smem[];
  short* As = smem;              // 2 slots x 16384 shorts (64 KiB)
  short* Bs = smem + 2 * SLOT;   // 2 slots x 16384 shorts (64 KiB)

  // XCD-aware swizzle: nwg=256 (%8==0, bijective)
  const int wg  = blockIdx.x;
  const int swz = (wg & 7) * 32 + (wg >> 3);
  const int tm = swz >> 3;              // 0..31
  const int tn = swz & 7;               // 0..7
  const int row0 = tm * BM, col0 = tn * BN;

  const int tid  = threadIdx.x;
  const int lane = tid & 63;
  const int wid  = tid >> 6;
  const int wr = (wid >> 2) * 128;      // 2 m-groups
  const int wc = (wid & 3) * 64;        // 4 n-groups

  // ---- fragment ds_read offsets (shorts), kh=0; kh=1 = offset ^ 32 ----
  // row r, k-slot slot = kh*4 + (lane>>4); phys = slot ^ (r&7)
  //  = (kh ^ ((r>>2)&1))*4 + ((lane>>4) ^ (r&3))
  // off(kh=0) = r*64 + ((lane>>4) ^ (r&3))*8 + (((r>>2)&1))*32; bit5 of rest is 0.
  const int g4 = lane >> 4;
  int offA[8], offB[4];
#pragma unroll
  for (int m = 0; m < 8; ++m) {
    const int r = wr + m * 16 + (lane & 15);
    offA[m] = r * 64 + ((g4 ^ (r & 3)) << 3) + (((r >> 2) & 1) << 5);
  }
#pragma unroll
  for (int n = 0; n < 4; ++n) {
    const int r = wc + n * 16 + (lane & 15);
    offB[n] = r * 64 + ((g4 ^ (r & 3)) << 3) + (((r >> 2) & 1) << 5);
  }

  // ---- staging mapping: load c in 0..7: row = (tid>>4) + c*32,
  // floats [ (tid&15)*4, +4 ) of the tile's 64-float k-range.
  // Per instruction: 4 rows x 256B contiguous (coalesced).
  const int lrow   = tid >> 4;          // 0..31
  const int lcol16 = (tid & 15) * 4;    // float col within tile
  const float* gA = X  + (size_t)(row0 + lrow) * HDIM + lcol16;
  const float* gB = Bm + (size_t)(col0 + lrow) * HDIM + lcol16;

  // ds_write (b64) offsets: row wrow=lrow+c*32, slot=(tid&15)>>1, half=tid&1
  // phys byte = wrow*128 + ((slot^(wrow&7))<<4) + half*8
  int offW[8];
#pragma unroll
  for (int c = 0; c < 8; ++c) {
    const int wrow = lrow + c * 32;
    offW[c] = wrow * 64 + ((((tid & 15) >> 1) ^ (wrow & 7)) << 3) + (tid & 1) * 4;
  }

#define ISSUE(dst, gp, t_) do {                                               \
    _Pragma("unroll") for (int c = 0; c < 8; ++c)                             \
      dst[c] = *(const f32x4*)((gp) + (size_t)c * 32 * HDIM + (t_) * KT);     \
  } while (0)

#define CVTWR(arr, base, sl) do {                                             \
    _Pragma("unroll") for (int c = 0; c < 8; ++c) {                           \
      s16x4 v;                                                                \
      v[0] = f2bf(arr[c][0]); v[1] = f2bf(arr[c][1]);                         \
      v[2] = f2bf(arr[c][2]); v[3] = f2bf(arr[c][3]);                         \
      *(s16x4*)&base[(sl) * SLOT + offW[c]] = v;                              \
    }                                                                         \
  } while (0)

#define PHASE(sl, khx, ACC_) do {                                             \
    s16x8 af[8], bfv[4];                                                      \
    _Pragma("unroll") for (int m = 0; m < 8; ++m)                             \
      af[m] = *(const s16x8*)&As[(sl) * SLOT + (offA[m] ^ (khx))];            \
    _Pragma("unroll") for (int n = 0; n < 4; ++n)                             \
      bfv[n] = *(const s16x8*)&Bs[(sl) * SLOT + (offB[n] ^ (khx))];           \
    __builtin_amdgcn_s_setprio(1);                                            \
    _Pragma("unroll") for (int m = 0; m < 8; ++m)                             \
      _Pragma("unroll") for (int n = 0; n < 4; ++n)                           \
        ACC_[m][n] = __builtin_amdgcn_mfma_f32_16x16x32_bf16(                 \
            af[m], bfv[n], ACC_[m][n], 0, 0, 0);                              \
    __builtin_amdgcn_s_setprio(0);                                            \
  } while (0)

  f32x4 acc[8][4] = {};
  f32x4 ar[8], br[8];

  // prologue: stage tile 0 -> slot 0
  ISSUE(ar, gA, 0);
  ISSUE(br, gB, 0);
  CVTWR(ar, As, 0);
  CVTWR(br, Bs, 0);
  __syncthreads();

  for (int j = 0; j < NIT - 1; ++j) {
    const int cur = j & 1;
    ISSUE(ar, gA, j + 1);               // A loads for next tile (early issue)
    PHASE(cur, 0, acc);                 // kh=0: 12 ds_read + 32 MFMA
    CVTWR(ar, As, cur ^ 1);             // A arrived (~1 phase of latency)
    ISSUE(br, gB, j + 1);               // B loads (covered by phase 1)
    PHASE(cur, 32, acc);                // kh=1
    CVTWR(br, Bs, cur ^ 1);
    __syncthreads();                    // slot swap fence (drains lgkm+vm free)
  }
  {
    const int cur = (NIT - 1) & 1;
    PHASE(cur, 0, acc);
    PHASE(cur, 32, acc);
  }

  // epilogue: C/D mapping col=lane&15, row=(lane>>4)*4+j [verified R1-R3]
  const int crow = row0 + wr + ((lane >> 4) << 2);
  const int ccol = col0 + wc + (lane & 15);
#pragma unroll
  for (int m = 0; m < 8; ++m)
#pragma unroll
    for (int n = 0; n < 4; ++n)
#pragma unroll
      for (int j = 0; j < 4; ++j)
        U[(size_t)(crow + m * 16 + j) * HDIM + ccol + n * 16] = acc[m][n][j];

#undef ISSUE
#undef CVTWR
#undef PHASE
}

// ---------------- scan pass 1: per-chunk local scan end values ---------------
__global__ void scan_pass1(const float* __restrict__ U,
                           const float* __restrict__ lam,
                           float* __restrict__ e) {
  const int c = (blockIdx.y * 256 + threadIdx.x) * 4;
  const int j = blockIdx.x;
  const f32x4 l4 = *(const f32x4*)&lam[c];
  f32x4 h = {0.f, 0.f, 0.f, 0.f};
  const float* up = U + (size_t)j * LCH * HDIM + c;
#pragma unroll 4
  for (int t = 0; t < LCH; ++t) {
    f32x4 u4 = *(const f32x4*)up;
    h = l4 * h + u4;
    up += HDIM;
  }
  *(f32x4*)&e[(size_t)j * HDIM + c] = h;
}

// ---------------- scan pass 2: carry scan over chunks (in-place on e) --------
__global__ void scan_carry(float* __restrict__ e, const float* __restrict__ lam) {
  const int c = (blockIdx.x * 256 + threadIdx.x) * 4;
  const f32x4 l4 = *(const f32x4*)&lam[c];
  f32x4 p = l4;
#pragma unroll
  for (int i = 0; i < 6; ++i) p = p * p;   // lam^64
  f32x4 E = {0.f, 0.f, 0.f, 0.f};
  for (int j = 0; j < GCH; ++j) {
    f32x4 ej = *(const f32x4*)&e[(size_t)j * HDIM + c];
    *(f32x4*)&e[(size_t)j * HDIM + c] = E;  // carry into chunk j = E_{j-1}
    E = p * E + ej;
  }
}

// ---------------- scan pass 3: final scan with carry, in-place U -> h --------
__global__ void scan_pass3(float* __restrict__ U, const float* __restrict__ lam,
                           const float* __restrict__ carry) {
  const int c = (blockIdx.y * 256 + threadIdx.x) * 4;
  const int j = blockIdx.x;
  const f32x4 l4 = *(const f32x4*)&lam[c];
  f32x4 h = *(const f32x4*)&carry[(size_t)j * HDIM + c];
  float* up = U + (size_t)j * LCH * HDIM + c;
#pragma unroll 4
  for (int t = 0; t < LCH; ++t) {
    f32x4 u4 = *(const f32x4*)up;
    h = l4 * h + u4;
    *(f32x4*)up = h;
    up += HDIM;
  }
}

extern "C" void kernel_launch(void* const* d_in, const int* in_sizes, int n_in,
                              void* d_out, int out_size, void* d_ws, size_t ws_size,
                              hipStream_t stream) {
  const float* X   = (const float*)d_in[0];
  const float* lam = (const float*)d_in[1];
  const float* Bm  = (const float*)d_in[2];
  float* U = (float*)d_out;              // u then h, in-place
  float* e = (float*)d_ws;               // 1 MB chunk carries

  // allow 128 KiB dynamic LDS (host-side, idempotent, capture-safe: proven R3)
  hipFuncSetAttribute((const void*)gemm_fused,
                      hipFuncAttributeMaxDynamicSharedMemorySize, 131072);

  gemm_fused<<<dim3((TDIM / BM) * (HDIM / BN)), dim3(512), 131072, stream>>>(
      X, Bm, U);
  scan_pass1<<<dim3(GCH, HDIM / 1024), dim3(256), 0, stream>>>(U, lam, e);
  scan_carry<<<dim3(HDIM / 1024), dim3(256), 0, stream>>>(e, lam);
  scan_pass3<<<dim3(GCH, HDIM / 1024), dim3(256), 0, stream>>>(U, lam, e);
}